// Round 6
// baseline (252.539 us; speedup 1.0000x reference)
//
#include <hip/hip_runtime.h>
#include <math.h>

// T=512, B=256, D=256, H=4. Wires 2,3 input-independent -> closed form (table
// kernel). GEMM: [131072 x 256] @ [256 x 8] via mfma_f32_16x16x32_bf16, one
// wave per 16-row tile (A: m=lane&15, k=quad*8+j; C/D: col=lane&15,
// row=quad*4+reg — HW-verified layouts). Scan: contractive recurrence ->
// chunked-parallel (16 chunks x 32, 40-step warm-up) with 2 chains/lane ILP.
#define TT 512
#define BB 256
#define DD 256
#define ROWS (TT * BB)          // 131072
#define INV2PI 0.15915494309189535f

typedef float v2f __attribute__((ext_vector_type(2)));
typedef float v4f __attribute__((ext_vector_type(4)));
typedef short s8v __attribute__((ext_vector_type(8)));

// ---------- small math helpers ----------
__device__ __forceinline__ v2f pkfma(v2f a, v2f b, v2f c) {
    return __builtin_elementwise_fma(a, b, c);
}
__device__ __forceinline__ v2f cos2(v2f a) {
    v2f r;
    r.x = __builtin_amdgcn_cosf(a.x);   // v_cos_f32: cos(2*pi*x)
    r.y = __builtin_amdgcn_cosf(a.y);
    return r;
}
// sigmoid(x), |x|<=1. Odd Taylor deg-7: max err ~2e-5.
__device__ __forceinline__ v2f sig2(v2f x) {
    v2f u = x * x;
    v2f p = pkfma(u, (v2f)(-2.1081349e-4f), (v2f)(2.0833333e-3f));
    p = pkfma(u, p, (v2f)(-2.0833333e-2f));
    p = pkfma(u, p, (v2f)(0.25f));
    return pkfma(x, p, (v2f)(0.5f));
}
// tanh(x), |x|<=~2.5: Pade CF4, err <2e-5.
__device__ __forceinline__ v2f tanh2(v2f x) {
    v2f u = x * x;
    v2f n = pkfma(u + (v2f)(105.0f), u, (v2f)(945.0f));
    v2f d = pkfma(pkfma(u, (v2f)(15.0f), (v2f)(420.0f)), u, (v2f)(945.0f));
    v2f r;
    r.x = __builtin_amdgcn_rcpf(d.x);
    r.y = __builtin_amdgcn_rcpf(d.y);
    return x * n * r;
}

// f32 -> bf16 round-to-nearest-even, packed pairs.
__device__ __forceinline__ uint32_t bfr(float f) {
    uint32_t b = __float_as_uint(f);
    return b + 0x7FFFu + ((b >> 16) & 1u);
}
__device__ __forceinline__ uint32_t packbf(float lo, float hi) {
    return (bfr(hi) & 0xFFFF0000u) | (bfr(lo) >> 16);
}
__device__ __forceinline__ s8v pack8(v4f lo, v4f hi) {
    union { uint32_t u[4]; s8v s; } r;
    r.u[0] = packbf(lo.x, lo.y);
    r.u[1] = packbf(lo.z, lo.w);
    r.u[2] = packbf(hi.x, hi.y);
    r.u[3] = packbf(hi.z, hi.w);
    return r.s;
}

// ---------- kernel 0: per-t constant tables (1 block) ----------
// hcf_g[t*8+j] = (b_j + phi_j + h2(t)*W[.,258] + h3(t)*W[.,259]) * INV2PI
// hob_g[t*2+w] = deterministic h_{t+1}[2+w]
__global__ __launch_bounds__(256) void qlstm_table(
    const float* __restrict__ Wf, const float* __restrict__ bf, const float* __restrict__ pf,
    const float* __restrict__ Wi, const float* __restrict__ bi, const float* __restrict__ pi,
    const float* __restrict__ Wu, const float* __restrict__ bu, const float* __restrict__ pu,
    const float* __restrict__ Wo, const float* __restrict__ bo, const float* __restrict__ po,
    float* __restrict__ hcf_g, float* __restrict__ hob_g) {
    const int tid = threadIdx.x;
    const float* Ws[4] = {Wf, Wi, Wu, Wo};
    const float* Bs[4] = {bf, bi, bu, bo};
    const float* Ps[4] = {pf, pi, pu, po};

    float l2fc[2], Scc[2], occ[2], ricc[2];
#pragma unroll
    for (int w = 0; w < 2; ++w) {
        const int q = w + 2;
        float fv = 1.0f / (1.0f + expf(-cosf(Ps[0][q])));
        float iv = 1.0f / (1.0f + expf(-cosf(Ps[1][q])));
        float gv = tanhf(cosf(Ps[2][q]));
        float ov = 1.0f / (1.0f + expf(-cosf(Ps[3][q])));
        l2fc[w] = log2f(fv);
        Scc[w] = iv * gv;
        occ[w] = ov;
        ricc[w] = 1.0f / (1.0f - fv);
    }
    float bb[8];
#pragma unroll
    for (int g = 0; g < 4; ++g)
#pragma unroll
        for (int wire = 0; wire < 2; ++wire) bb[g * 2 + wire] = Bs[g][wire] + Ps[g][wire];

    for (int t = tid; t < TT; t += 256) {
        float h2 = occ[0] * tanhf(Scc[0] * (1.0f - exp2f((float)t * l2fc[0])) * ricc[0]);
        float h3 = occ[1] * tanhf(Scc[1] * (1.0f - exp2f((float)t * l2fc[1])) * ricc[1]);
        float ho2 = occ[0] * tanhf(Scc[0] * (1.0f - exp2f((float)(t + 1) * l2fc[0])) * ricc[0]);
        float ho3 = occ[1] * tanhf(Scc[1] * (1.0f - exp2f((float)(t + 1) * l2fc[1])) * ricc[1]);
#pragma unroll
        for (int g = 0; g < 4; ++g)
#pragma unroll
            for (int wire = 0; wire < 2; ++wire)
                hcf_g[t * 8 + g * 2 + wire] =
                    (bb[g * 2 + wire] + h2 * Ws[g][wire * 260 + 258] + h3 * Ws[g][wire * 260 + 259]) * INV2PI;
        hob_g[t * 2] = ho2;
        hob_g[t * 2 + 1] = ho3;
    }
}

// ---------- kernel 1: MFMA GEMM ----------
// tile = 16 consecutive rows (same t since 16 | 256). One wave per tile.
__global__ __launch_bounds__(256) void qlstm_gemm(
    const float* __restrict__ x,
    const float* __restrict__ Wf, const float* __restrict__ Wi,
    const float* __restrict__ Wu, const float* __restrict__ Wo,
    const float* __restrict__ hcf_g, const float* __restrict__ hob_g,
    float* __restrict__ Z, float* __restrict__ out) {
    const int tid = threadIdx.x;
    const int lane = tid & 63;
    const int tile = blockIdx.x * 4 + (tid >> 6);  // 0..8191
    const int rbase = tile * 16;
    const int t = tile >> 4;
    const int m = lane & 15;   // A row / B col / D col
    const int q = lane >> 4;   // k-quad
    const float* Ws[4] = {Wf, Wi, Wu, Wo};

    // B fragments: B[k][n] with n = lane&15 (cols 8..15 duplicate 0..7, ignored).
    const int j = m & 7;
    const float* wrow = Ws[j >> 1] + (j & 1) * 260 + q * 8;
    s8v bfrag[8];
#pragma unroll
    for (int kk = 0; kk < 8; ++kk) {
        v4f wlo = *(const v4f*)(wrow + kk * 32);
        v4f whi = *(const v4f*)(wrow + kk * 32 + 4);
        bfrag[kk] = pack8(wlo, whi);
    }

    // A: lane reads x[rbase+m][kk*32 + q*8 .. +7]
    const float* xrow = x + (size_t)(rbase + m) * DD + q * 8;
    v4f acc = {0.f, 0.f, 0.f, 0.f};
#pragma unroll
    for (int kk = 0; kk < 8; ++kk) {
        v4f xlo = *(const v4f*)(xrow + kk * 32);
        v4f xhi = *(const v4f*)(xrow + kk * 32 + 4);
        s8v afrag = pack8(xlo, xhi);
        acc = __builtin_amdgcn_mfma_f32_16x16x32_bf16(afrag, bfrag[kk], acc, 0, 0, 0);
    }

    // Epilogue: D col = m, row = q*4+r. Z = dot*INV2PI + hcf[t][j].
    const float hc = hcf_g[t * 8 + j];
    if (m < 8) {
#pragma unroll
        for (int r = 0; r < 4; ++r) {
            const int row = rbase + q * 4 + r;
            Z[(size_t)row * 8 + m] = acc[r] * INV2PI + hc;
        }
    }
    if (lane >= 48) {  // 16 lanes: deterministic out cols 2,3 for the tile's rows
        const int row = rbase + (lane - 48);
        *(float2*)(out + (size_t)row * 4 + 2) = *(const float2*)&hob_g[t * 2];
    }
}

// ---------- kernel 2: chunked scan, 2 chains per lane ----------
struct Ch {
    v2f h, c;
    v4f zb[4][2];
    int tw, t0;
};

__device__ __forceinline__ void ch_init(Ch& ch, const float* Zb, int tw, int t0) {
    ch.h = (v2f)(0.f);
    ch.c = (v2f)(0.f);
    ch.tw = tw;
    ch.t0 = t0;
#pragma unroll
    for (int s = 0; s < 4; ++s) {
        ch.zb[s][0] = *(const v4f*)(Zb + (size_t)(tw + s) * 2048);
        ch.zb[s][1] = *(const v4f*)(Zb + (size_t)(tw + s) * 2048 + 4);
    }
}

__device__ __forceinline__ void ch_step(Ch& ch, int s, int slot, const float* Zb,
                                        float* outp, const v2f* wa, const v2f* wb) {
    const int t = ch.tw + s;
    v4f zA = ch.zb[slot][0], zB = ch.zb[slot][1];
    int tp = t + 4;
    tp = (tp < TT) ? tp : (TT - 1);  // clamped prefetch (always valid)
    ch.zb[slot][0] = *(const v4f*)(Zb + (size_t)tp * 2048);
    ch.zb[slot][1] = *(const v4f*)(Zb + (size_t)tp * 2048 + 4);
    v2f zf = {zA.x, zA.y}, zi = {zA.z, zA.w}, zu = {zB.x, zB.y}, zo = {zB.z, zB.w};
    v2f h0s = (v2f)(ch.h.x), h1s = (v2f)(ch.h.y);
    v2f af = pkfma(h0s, wa[0], pkfma(h1s, wb[0], zf));
    v2f ai = pkfma(h0s, wa[1], pkfma(h1s, wb[1], zi));
    v2f au = pkfma(h0s, wa[2], pkfma(h1s, wb[2], zu));
    v2f ao = pkfma(h0s, wa[3], pkfma(h1s, wb[3], zo));
    v2f f = sig2(cos2(af));
    v2f i = sig2(cos2(ai));
    v2f g = tanh2(cos2(au));
    v2f o = sig2(cos2(ao));
    ch.c = pkfma(f, ch.c, i * g);
    ch.h = o * tanh2(ch.c);
    if (t >= ch.t0)
        *(v2f*)(outp + (size_t)t * 1024) = ch.h;  // cols 0,1
}

// Grid: 32 blocks x 64. Block -> (cpair 0..7, bgroup 0..3); lane = batch elem.
// Chain A: chunk cpair (t0=cpair*32); chain B: chunk cpair+8. Warm-up 40 steps.
__global__ __launch_bounds__(64) void qlstm_scan(
    const float* __restrict__ Z,
    const float* __restrict__ Wf, const float* __restrict__ pf,
    const float* __restrict__ Wi, const float* __restrict__ pi,
    const float* __restrict__ Wu, const float* __restrict__ pu,
    const float* __restrict__ Wo, const float* __restrict__ po,
    float* __restrict__ out) {
    const int tid = threadIdx.x;
    const int cpair = blockIdx.x >> 2;          // 0..7
    const int b = (blockIdx.x & 3) * 64 + tid;  // 0..255
    const float* Ws[4] = {Wf, Wi, Wu, Wo};
    const float* Ps[4] = {pf, pi, pu, po};

    // deterministic finals (used only by cpair 7 / chunk 15)
    float cd[2], hd[2];
#pragma unroll
    for (int w = 0; w < 2; ++w) {
        const int q = w + 2;
        float fv = 1.0f / (1.0f + expf(-cosf(Ps[0][q])));
        float iv = 1.0f / (1.0f + expf(-cosf(Ps[1][q])));
        float gv = tanhf(cosf(Ps[2][q]));
        float ov = 1.0f / (1.0f + expf(-cosf(Ps[3][q])));
        float l2f = log2f(fv);
        float S = iv * gv;
        float ric = 1.0f / (1.0f - fv);
        cd[w] = S * (1.0f - exp2f(512.0f * l2f)) * ric;
        hd[w] = ov * tanhf(cd[w]);
    }

    v2f wa[4], wb[4];
#pragma unroll
    for (int g = 0; g < 4; ++g) {
        wa[g].x = Ws[g][256] * INV2PI;
        wa[g].y = Ws[g][260 + 256] * INV2PI;
        wb[g].x = Ws[g][257] * INV2PI;
        wb[g].y = Ws[g][260 + 257] * INV2PI;
    }

    const int t0A = cpair * 32;
    const int twA = (t0A >= 40) ? t0A - 40 : 0;
    const int lenA = t0A + 32 - twA;   // 32, 64, or 72 (all %4==0)
    const int preA = 72 - lenA;        // 40, 8, or 0 (all %4==0)
    const int t0B = (cpair + 8) * 32;
    const int twB = t0B - 40;

    const float* Zb = Z + (size_t)b * 8;
    float* outp = out + (size_t)b * 4;

    Ch A, B;
    ch_init(A, Zb, twA, t0A);
    ch_init(B, Zb, twB, t0B);

#pragma unroll 4
    for (int s = 0; s < preA; ++s)
        ch_step(B, s, s & 3, Zb, outp, wa, wb);
#pragma unroll 4
    for (int s = 0; s < lenA; ++s) {
        ch_step(A, s, s & 3, Zb, outp, wa, wb);
        ch_step(B, preA + s, s & 3, Zb, outp, wa, wb);  // preA%4==0 -> ring stays aligned
    }

    if (cpair == 7) {
        *(float4*)(out + (size_t)TT * BB * 4 + (size_t)b * 4) =
            make_float4(B.h.x, B.h.y, hd[0], hd[1]);
        *(float4*)(out + (size_t)TT * BB * 4 + (size_t)BB * 4 + (size_t)b * 4) =
            make_float4(B.c.x, B.c.y, cd[0], cd[1]);
    }
}

extern "C" void kernel_launch(void* const* d_in, const int* in_sizes, int n_in,
                              void* d_out, int out_size, void* d_ws, size_t ws_size,
                              hipStream_t stream) {
    (void)in_sizes; (void)n_in; (void)out_size; (void)ws_size;
    const float* x  = (const float*)d_in[0];
    const float* Wf = (const float*)d_in[1];
    const float* bf = (const float*)d_in[2];
    const float* pf = (const float*)d_in[3];
    const float* Wi = (const float*)d_in[4];
    const float* bi = (const float*)d_in[5];
    const float* pi = (const float*)d_in[6];
    const float* Wu = (const float*)d_in[7];
    const float* bu = (const float*)d_in[8];
    const float* pu = (const float*)d_in[9];
    const float* Wo = (const float*)d_in[10];
    const float* bo = (const float*)d_in[11];
    const float* po = (const float*)d_in[12];
    float* out = (float*)d_out;
    float* Z = (float*)d_ws;                       // 4 MiB
    float* hcf_g = Z + (size_t)ROWS * 8;           // 16 KiB
    float* hob_g = hcf_g + TT * 8;                 // 4 KiB

    qlstm_table<<<1, 256, 0, stream>>>(Wf, bf, pf, Wi, bi, pi, Wu, bu, pu,
                                       Wo, bo, po, hcf_g, hob_g);
    qlstm_gemm<<<2048, 256, 0, stream>>>(x, Wf, Wi, Wu, Wo, hcf_g, hob_g, Z, out);
    qlstm_scan<<<32, 64, 0, stream>>>(Z, Wf, pf, Wi, pi, Wu, pu, Wo, po, out);
}

// Round 7
// 250.184 us; speedup vs baseline: 1.0094x; 1.0094x over previous
//
#include <hip/hip_runtime.h>
#include <math.h>

// T=512, B=256, D=256, H=4. Wires 2,3 input-independent -> closed form (table
// kernel). GEMM: one wave per row (64 lanes x float4 = whole 256-float row,
// coalesced), 8 dots via 10-shuffle butterfly. Scan: contractive recurrence ->
// chunked-parallel (16 chunks x 32, 40-step warm-up), 2 chains/lane ILP.
#define TT 512
#define BB 256
#define DD 256
#define ROWS (TT * BB)          // 131072
#define INV2PI 0.15915494309189535f

typedef float v2f __attribute__((ext_vector_type(2)));
typedef float v4f __attribute__((ext_vector_type(4)));

__device__ __forceinline__ v2f pkfma(v2f a, v2f b, v2f c) {
    return __builtin_elementwise_fma(a, b, c);
}
__device__ __forceinline__ v2f cos2(v2f a) {
    v2f r;
    r.x = __builtin_amdgcn_cosf(a.x);   // v_cos_f32: cos(2*pi*x)
    r.y = __builtin_amdgcn_cosf(a.y);
    return r;
}
// sigmoid(x), |x|<=1. Odd Taylor deg-7: max err ~2e-5.
__device__ __forceinline__ v2f sig2(v2f x) {
    v2f u = x * x;
    v2f p = pkfma(u, (v2f)(-2.1081349e-4f), (v2f)(2.0833333e-3f));
    p = pkfma(u, p, (v2f)(-2.0833333e-2f));
    p = pkfma(u, p, (v2f)(0.25f));
    return pkfma(x, p, (v2f)(0.5f));
}
// tanh(x), |x|<=~2.5: Pade CF4, err <2e-5.
__device__ __forceinline__ v2f tanh2(v2f x) {
    v2f u = x * x;
    v2f n = pkfma(u + (v2f)(105.0f), u, (v2f)(945.0f));
    v2f d = pkfma(pkfma(u, (v2f)(15.0f), (v2f)(420.0f)), u, (v2f)(945.0f));
    v2f r;
    r.x = __builtin_amdgcn_rcpf(d.x);
    r.y = __builtin_amdgcn_rcpf(d.y);
    return x * n * r;
}

// Multi-value butterfly: sum p[0..7] across 64 lanes, 10 shuffles.
// Lane l ends with the sum for value v = 4*(l&1) + 2*((l>>1)&1) + ((l>>2)&1).
__device__ __forceinline__ float reduce8(float p[8], int lane) {
    const bool b0 = lane & 1;
#pragma unroll
    for (int k = 0; k < 4; ++k) {
        float send = b0 ? p[k] : p[k + 4];
        float q = __shfl_xor(send, 1, 64);
        p[k] = (b0 ? p[k + 4] : p[k]) + q;
    }
    const bool b1 = lane & 2;
#pragma unroll
    for (int k = 0; k < 2; ++k) {
        float send = b1 ? p[k] : p[k + 2];
        float q = __shfl_xor(send, 2, 64);
        p[k] = (b1 ? p[k + 2] : p[k]) + q;
    }
    const bool b2 = lane & 4;
    {
        float send = b2 ? p[0] : p[1];
        float q = __shfl_xor(send, 4, 64);
        p[0] = (b2 ? p[1] : p[0]) + q;
    }
    p[0] += __shfl_xor(p[0], 8, 64);
    p[0] += __shfl_xor(p[0], 16, 64);
    p[0] += __shfl_xor(p[0], 32, 64);
    return p[0];
}

// ---------- kernel 0: per-t constant tables (1 block) ----------
__global__ __launch_bounds__(256) void qlstm_table(
    const float* __restrict__ Wf, const float* __restrict__ bf, const float* __restrict__ pf,
    const float* __restrict__ Wi, const float* __restrict__ bi, const float* __restrict__ pi,
    const float* __restrict__ Wu, const float* __restrict__ bu, const float* __restrict__ pu,
    const float* __restrict__ Wo, const float* __restrict__ bo, const float* __restrict__ po,
    float* __restrict__ hcf_g, float* __restrict__ hob_g) {
    const int tid = threadIdx.x;
    const float* Ws[4] = {Wf, Wi, Wu, Wo};
    const float* Bs[4] = {bf, bi, bu, bo};
    const float* Ps[4] = {pf, pi, pu, po};

    float l2fc[2], Scc[2], occ[2], ricc[2];
#pragma unroll
    for (int w = 0; w < 2; ++w) {
        const int q = w + 2;
        float fv = 1.0f / (1.0f + expf(-cosf(Ps[0][q])));
        float iv = 1.0f / (1.0f + expf(-cosf(Ps[1][q])));
        float gv = tanhf(cosf(Ps[2][q]));
        float ov = 1.0f / (1.0f + expf(-cosf(Ps[3][q])));
        l2fc[w] = log2f(fv);
        Scc[w] = iv * gv;
        occ[w] = ov;
        ricc[w] = 1.0f / (1.0f - fv);
    }
    float bb[8];
#pragma unroll
    for (int g = 0; g < 4; ++g)
#pragma unroll
        for (int wire = 0; wire < 2; ++wire) bb[g * 2 + wire] = Bs[g][wire] + Ps[g][wire];

    for (int t = tid; t < TT; t += 256) {
        float h2 = occ[0] * tanhf(Scc[0] * (1.0f - exp2f((float)t * l2fc[0])) * ricc[0]);
        float h3 = occ[1] * tanhf(Scc[1] * (1.0f - exp2f((float)t * l2fc[1])) * ricc[1]);
        float ho2 = occ[0] * tanhf(Scc[0] * (1.0f - exp2f((float)(t + 1) * l2fc[0])) * ricc[0]);
        float ho3 = occ[1] * tanhf(Scc[1] * (1.0f - exp2f((float)(t + 1) * l2fc[1])) * ricc[1]);
#pragma unroll
        for (int g = 0; g < 4; ++g)
#pragma unroll
            for (int wire = 0; wire < 2; ++wire)
                hcf_g[t * 8 + g * 2 + wire] =
                    (bb[g * 2 + wire] + h2 * Ws[g][wire * 260 + 258] + h3 * Ws[g][wire * 260 + 259]) * INV2PI;
        hob_g[t * 2] = ho2;
        hob_g[t * 2 + 1] = ho3;
    }
}

// ---------- kernel 1: GEMM, one wave per row (coalesced) ----------
__global__ __launch_bounds__(256) void qlstm_gemm(
    const float* __restrict__ x,
    const float* __restrict__ Wf, const float* __restrict__ Wi,
    const float* __restrict__ Wu, const float* __restrict__ Wo,
    const float* __restrict__ hcf_g, const float* __restrict__ hob_g,
    float* __restrict__ Z, float* __restrict__ out) {
    const int tid = threadIdx.x;
    const int lane = tid & 63;
    const int wid = (blockIdx.x * 256 + tid) >> 6;  // 0..8191
    const float* Ws[4] = {Wf, Wi, Wu, Wo};

    float4 wv[8];
#pragma unroll
    for (int g = 0; g < 4; ++g)
#pragma unroll
        for (int wire = 0; wire < 2; ++wire)
            wv[g * 2 + wire] = *(const float4*)(Ws[g] + wire * 260 + 4 * lane);
    const int v = ((lane & 1) << 2) | (lane & 2) | ((lane >> 2) & 1);

#pragma unroll
    for (int k = 0; k < 16; k += 4) {
        v4f xv[4];
#pragma unroll
        for (int j = 0; j < 4; ++j) {
            const int r = wid + (k + j) * 8192;
            xv[j] = *(const v4f*)(x + (size_t)r * DD + 4 * lane);  // cached: x fits L3
        }
        float s[4];
#pragma unroll
        for (int j = 0; j < 4; ++j) {
            float p[8];
#pragma unroll
            for (int m = 0; m < 8; ++m)
                p[m] = xv[j].x * wv[m].x + xv[j].y * wv[m].y + xv[j].z * wv[m].z + xv[j].w * wv[m].w;
            s[j] = reduce8(p, lane);
        }
        if (lane < 8) {
#pragma unroll
            for (int j = 0; j < 4; ++j) {
                const int r = wid + (k + j) * 8192;
                Z[(size_t)r * 8 + v] = s[j] * INV2PI + hcf_g[((r >> 8) << 3) + v];
            }
        } else if (lane < 12) {
            const int r = wid + (k + lane - 8) * 8192;
            *(float2*)(out + (size_t)r * 4 + 2) = *(const float2*)&hob_g[(r >> 8) * 2];
        }
    }
}

// ---------- kernel 2: chunked scan, 2 chains per lane ----------
struct Ch {
    v2f h, c;
    v4f zb[4][2];
    int tw, t0;
};

__device__ __forceinline__ void ch_init(Ch& ch, const float* Zb, int tw, int t0) {
    ch.h = (v2f)(0.f);
    ch.c = (v2f)(0.f);
    ch.tw = tw;
    ch.t0 = t0;
#pragma unroll
    for (int s = 0; s < 4; ++s) {
        ch.zb[s][0] = *(const v4f*)(Zb + (size_t)(tw + s) * 2048);
        ch.zb[s][1] = *(const v4f*)(Zb + (size_t)(tw + s) * 2048 + 4);
    }
}

__device__ __forceinline__ void ch_step(Ch& ch, int s, int slot, const float* Zb,
                                        float* outp, const v2f* wa, const v2f* wb) {
    const int t = ch.tw + s;
    v4f zA = ch.zb[slot][0], zB = ch.zb[slot][1];
    int tp = t + 4;
    tp = (tp < TT) ? tp : (TT - 1);  // clamped prefetch (always valid)
    ch.zb[slot][0] = *(const v4f*)(Zb + (size_t)tp * 2048);
    ch.zb[slot][1] = *(const v4f*)(Zb + (size_t)tp * 2048 + 4);
    v2f zf = {zA.x, zA.y}, zi = {zA.z, zA.w}, zu = {zB.x, zB.y}, zo = {zB.z, zB.w};
    v2f h0s = (v2f)(ch.h.x), h1s = (v2f)(ch.h.y);
    v2f af = pkfma(h0s, wa[0], pkfma(h1s, wb[0], zf));
    v2f ai = pkfma(h0s, wa[1], pkfma(h1s, wb[1], zi));
    v2f au = pkfma(h0s, wa[2], pkfma(h1s, wb[2], zu));
    v2f ao = pkfma(h0s, wa[3], pkfma(h1s, wb[3], zo));
    v2f f = sig2(cos2(af));
    v2f i = sig2(cos2(ai));
    v2f g = tanh2(cos2(au));
    v2f o = sig2(cos2(ao));
    ch.c = pkfma(f, ch.c, i * g);
    ch.h = o * tanh2(ch.c);
    if (t >= ch.t0)
        *(v2f*)(outp + (size_t)t * 1024) = ch.h;  // cols 0,1
}

// Grid: 32 blocks x 64. Block -> (cpair 0..7, bgroup 0..3); lane = batch elem.
// Chain A: chunk cpair; chain B: chunk cpair+8. Warm-up 40 steps from h=c=0.
__global__ __launch_bounds__(64) void qlstm_scan(
    const float* __restrict__ Z,
    const float* __restrict__ Wf, const float* __restrict__ pf,
    const float* __restrict__ Wi, const float* __restrict__ pi,
    const float* __restrict__ Wu, const float* __restrict__ pu,
    const float* __restrict__ Wo, const float* __restrict__ po,
    float* __restrict__ out) {
    const int tid = threadIdx.x;
    const int cpair = blockIdx.x >> 2;          // 0..7
    const int b = (blockIdx.x & 3) * 64 + tid;  // 0..255
    const float* Ws[4] = {Wf, Wi, Wu, Wo};
    const float* Ps[4] = {pf, pi, pu, po};

    // deterministic finals (used only by cpair 7 / chunk 15)
    float cd[2], hd[2];
#pragma unroll
    for (int w = 0; w < 2; ++w) {
        const int q = w + 2;
        float fv = 1.0f / (1.0f + expf(-cosf(Ps[0][q])));
        float iv = 1.0f / (1.0f + expf(-cosf(Ps[1][q])));
        float gv = tanhf(cosf(Ps[2][q]));
        float ov = 1.0f / (1.0f + expf(-cosf(Ps[3][q])));
        float l2f = log2f(fv);
        float S = iv * gv;
        float ric = 1.0f / (1.0f - fv);
        cd[w] = S * (1.0f - exp2f(512.0f * l2f)) * ric;
        hd[w] = ov * tanhf(cd[w]);
    }

    v2f wa[4], wb[4];
#pragma unroll
    for (int g = 0; g < 4; ++g) {
        wa[g].x = Ws[g][256] * INV2PI;
        wa[g].y = Ws[g][260 + 256] * INV2PI;
        wb[g].x = Ws[g][257] * INV2PI;
        wb[g].y = Ws[g][260 + 257] * INV2PI;
    }

    const int t0A = cpair * 32;
    const int twA = (t0A >= 40) ? t0A - 40 : 0;
    const int lenA = t0A + 32 - twA;   // 32, 64, or 72 (all %4==0)
    const int preA = 72 - lenA;        // 40, 8, or 0 (all %4==0)
    const int t0B = (cpair + 8) * 32;
    const int twB = t0B - 40;

    const float* Zb = Z + (size_t)b * 8;
    float* outp = out + (size_t)b * 4;

    Ch A, B;
    ch_init(A, Zb, twA, t0A);
    ch_init(B, Zb, twB, t0B);

#pragma unroll 4
    for (int s = 0; s < preA; ++s)
        ch_step(B, s, s & 3, Zb, outp, wa, wb);
#pragma unroll 4
    for (int s = 0; s < lenA; ++s) {
        ch_step(A, s, s & 3, Zb, outp, wa, wb);
        ch_step(B, preA + s, s & 3, Zb, outp, wa, wb);  // preA%4==0 -> ring aligned
    }

    if (cpair == 7) {
        *(float4*)(out + (size_t)TT * BB * 4 + (size_t)b * 4) =
            make_float4(B.h.x, B.h.y, hd[0], hd[1]);
        *(float4*)(out + (size_t)TT * BB * 4 + (size_t)BB * 4 + (size_t)b * 4) =
            make_float4(B.c.x, B.c.y, cd[0], cd[1]);
    }
}

extern "C" void kernel_launch(void* const* d_in, const int* in_sizes, int n_in,
                              void* d_out, int out_size, void* d_ws, size_t ws_size,
                              hipStream_t stream) {
    (void)in_sizes; (void)n_in; (void)out_size; (void)ws_size;
    const float* x  = (const float*)d_in[0];
    const float* Wf = (const float*)d_in[1];
    const float* bf = (const float*)d_in[2];
    const float* pf = (const float*)d_in[3];
    const float* Wi = (const float*)d_in[4];
    const float* bi = (const float*)d_in[5];
    const float* pi = (const float*)d_in[6];
    const float* Wu = (const float*)d_in[7];
    const float* bu = (const float*)d_in[8];
    const float* pu = (const float*)d_in[9];
    const float* Wo = (const float*)d_in[10];
    const float* bo = (const float*)d_in[11];
    const float* po = (const float*)d_in[12];
    float* out = (float*)d_out;
    float* Z = (float*)d_ws;                       // 4 MiB
    float* hcf_g = Z + (size_t)ROWS * 8;           // 16 KiB
    float* hob_g = hcf_g + TT * 8;                 // 4 KiB

    qlstm_table<<<1, 256, 0, stream>>>(Wf, bf, pf, Wi, bi, pi, Wu, bu, pu,
                                       Wo, bo, po, hcf_g, hob_g);
    qlstm_gemm<<<2048, 256, 0, stream>>>(x, Wf, Wi, Wu, Wo, hcf_g, hob_g, Z, out);
    qlstm_scan<<<32, 64, 0, stream>>>(Z, Wf, pf, Wi, pi, Wu, pu, Wo, po, out);
}

// Round 8
// 233.380 us; speedup vs baseline: 1.0821x; 1.0720x over previous
//
#include <hip/hip_runtime.h>
#include <math.h>

// T=512, B=256, D=256, H=4. Wires 2,3 input-independent -> closed form, inline
// per-block table in gemm (R5-proven structure). GEMM: one wave per row
// (64 lanes x float4 = whole row, coalesced), 8 dots via 10-shuffle butterfly.
// Scan: contractive recurrence (|df/dc| <= ~0.75) -> chunked-parallel:
// 16 chunks x 32 steps, 24-step warm-up from h=c=0 (0.75^24*3 ~ 3e-3 error).
#define TT 512
#define BB 256
#define DD 256
#define ROWS (TT * BB)          // 131072
#define INV2PI 0.15915494309189535f
#define CHUNK 32
#define WARM 24
#define NCH (TT / CHUNK)        // 16

typedef float v2f __attribute__((ext_vector_type(2)));
typedef float v4f __attribute__((ext_vector_type(4)));

__device__ __forceinline__ v2f pkfma(v2f a, v2f b, v2f c) {
    return __builtin_elementwise_fma(a, b, c);
}
__device__ __forceinline__ v2f cos2(v2f a) {
    v2f r;
    r.x = __builtin_amdgcn_cosf(a.x);   // v_cos_f32: cos(2*pi*x)
    r.y = __builtin_amdgcn_cosf(a.y);
    return r;
}
// sigmoid(x), |x|<=1. Odd Taylor deg-7: max err ~2e-5.
__device__ __forceinline__ v2f sig2(v2f x) {
    v2f u = x * x;
    v2f p = pkfma(u, (v2f)(-2.1081349e-4f), (v2f)(2.0833333e-3f));
    p = pkfma(u, p, (v2f)(-2.0833333e-2f));
    p = pkfma(u, p, (v2f)(0.25f));
    return pkfma(x, p, (v2f)(0.5f));
}
// tanh(x), |x|<=~2.5: Pade CF4, err <2e-5.
__device__ __forceinline__ v2f tanh2(v2f x) {
    v2f u = x * x;
    v2f n = pkfma(u + (v2f)(105.0f), u, (v2f)(945.0f));
    v2f d = pkfma(pkfma(u, (v2f)(15.0f), (v2f)(420.0f)), u, (v2f)(945.0f));
    v2f r;
    r.x = __builtin_amdgcn_rcpf(d.x);
    r.y = __builtin_amdgcn_rcpf(d.y);
    return x * n * r;
}

// Multi-value butterfly: sum p[0..7] across 64 lanes, 10 shuffles.
// Lane l ends with the sum for value v = 4*(l&1) + 2*((l>>1)&1) + ((l>>2)&1).
__device__ __forceinline__ float reduce8(float p[8], int lane) {
    const bool b0 = lane & 1;
#pragma unroll
    for (int k = 0; k < 4; ++k) {
        float send = b0 ? p[k] : p[k + 4];
        float q = __shfl_xor(send, 1, 64);
        p[k] = (b0 ? p[k + 4] : p[k]) + q;
    }
    const bool b1 = lane & 2;
#pragma unroll
    for (int k = 0; k < 2; ++k) {
        float send = b1 ? p[k] : p[k + 2];
        float q = __shfl_xor(send, 2, 64);
        p[k] = (b1 ? p[k + 2] : p[k]) + q;
    }
    const bool b2 = lane & 4;
    {
        float send = b2 ? p[0] : p[1];
        float q = __shfl_xor(send, 4, 64);
        p[0] = (b2 ? p[1] : p[0]) + q;
    }
    p[0] += __shfl_xor(p[0], 8, 64);
    p[0] += __shfl_xor(p[0], 16, 64);
    p[0] += __shfl_xor(p[0], 32, 64);
    return p[0];
}

// Kernel A: Z[t,b,j] = (x[t,b,:].W_j)*INV2PI + hc[t][j]; out[t][b][2..3] = det h.
__global__ __launch_bounds__(256) void qlstm_gemm(
    const float* __restrict__ x,
    const float* __restrict__ Wf, const float* __restrict__ bf, const float* __restrict__ pf,
    const float* __restrict__ Wi, const float* __restrict__ bi, const float* __restrict__ pi,
    const float* __restrict__ Wu, const float* __restrict__ bu, const float* __restrict__ pu,
    const float* __restrict__ Wo, const float* __restrict__ bo, const float* __restrict__ po,
    float* __restrict__ Z, float* __restrict__ out) {
    __shared__ float hcf[TT * 8];   // 16 KB: per-t constant part of angle (revolutions)
    __shared__ float hob[TT * 2];   // 4 KB:  h_{t+1}[2], h_{t+1}[3]
    const int tid = threadIdx.x;
    const float* Ws[4] = {Wf, Wi, Wu, Wo};
    const float* Bs[4] = {bf, bi, bu, bo};
    const float* Ps[4] = {pf, pi, pu, po};

    float l2fc[2], Scc[2], occ[2], ricc[2];
#pragma unroll
    for (int w = 0; w < 2; ++w) {
        const int q = w + 2;
        float fv = 1.0f / (1.0f + expf(-cosf(Ps[0][q])));
        float iv = 1.0f / (1.0f + expf(-cosf(Ps[1][q])));
        float gv = tanhf(cosf(Ps[2][q]));
        float ov = 1.0f / (1.0f + expf(-cosf(Ps[3][q])));
        l2fc[w] = log2f(fv);
        Scc[w] = iv * gv;
        occ[w] = ov;
        ricc[w] = 1.0f / (1.0f - fv);
    }
    float bb[8];
#pragma unroll
    for (int g = 0; g < 4; ++g)
#pragma unroll
        for (int wire = 0; wire < 2; ++wire) bb[g * 2 + wire] = Bs[g][wire] + Ps[g][wire];

    for (int t = tid; t < TT; t += 256) {
        float h2 = occ[0] * tanhf(Scc[0] * (1.0f - exp2f((float)t * l2fc[0])) * ricc[0]);
        float h3 = occ[1] * tanhf(Scc[1] * (1.0f - exp2f((float)t * l2fc[1])) * ricc[1]);
        float ho2 = occ[0] * tanhf(Scc[0] * (1.0f - exp2f((float)(t + 1) * l2fc[0])) * ricc[0]);
        float ho3 = occ[1] * tanhf(Scc[1] * (1.0f - exp2f((float)(t + 1) * l2fc[1])) * ricc[1]);
#pragma unroll
        for (int g = 0; g < 4; ++g)
#pragma unroll
            for (int wire = 0; wire < 2; ++wire)
                hcf[t * 8 + g * 2 + wire] =
                    (bb[g * 2 + wire] + h2 * Ws[g][wire * 260 + 258] + h3 * Ws[g][wire * 260 + 259]) * INV2PI;
        hob[t * 2] = ho2;
        hob[t * 2 + 1] = ho3;
    }
    __syncthreads();

    const int lane = tid & 63;
    const int wid = (blockIdx.x * 256 + tid) >> 6;  // 0..8191
    float4 wv[8];
#pragma unroll
    for (int g = 0; g < 4; ++g)
#pragma unroll
        for (int wire = 0; wire < 2; ++wire)
            wv[g * 2 + wire] = *(const float4*)(Ws[g] + wire * 260 + 4 * lane);
    const int v = ((lane & 1) << 2) | (lane & 2) | ((lane >> 2) & 1);

#pragma unroll
    for (int k = 0; k < 16; k += 4) {
        v4f xv[4];
#pragma unroll
        for (int j = 0; j < 4; ++j) {
            const int r = wid + (k + j) * 8192;
            xv[j] = *(const v4f*)(x + (size_t)r * DD + 4 * lane);
        }
        float s[4];
#pragma unroll
        for (int j = 0; j < 4; ++j) {
            float p[8];
#pragma unroll
            for (int m = 0; m < 8; ++m)
                p[m] = xv[j].x * wv[m].x + xv[j].y * wv[m].y + xv[j].z * wv[m].z + xv[j].w * wv[m].w;
            s[j] = reduce8(p, lane);
        }
        if (lane < 8) {
#pragma unroll
            for (int j = 0; j < 4; ++j) {
                const int r = wid + (k + j) * 8192;
                Z[(size_t)r * 8 + v] = s[j] * INV2PI + hcf[((r >> 8) << 3) + v];
            }
        } else if (lane < 12) {
            const int r = wid + (k + lane - 8) * 8192;
            *(float2*)(out + (size_t)r * 4 + 2) = *(const float2*)&hob[(r >> 8) * 2];
        }
    }
}

// Kernel B: chunked-parallel scan. Grid = NCH*4 blocks x 64 threads.
// block -> (chunk, bgroup); lane = batch elem. Warm-up from h=c=0 at
// tw = max(0, t0-WARM), emit CHUNK steps.
__global__ __launch_bounds__(64) void qlstm_scan(
    const float* __restrict__ Z,
    const float* __restrict__ Wf, const float* __restrict__ pf,
    const float* __restrict__ Wi, const float* __restrict__ pi,
    const float* __restrict__ Wu, const float* __restrict__ pu,
    const float* __restrict__ Wo, const float* __restrict__ po,
    float* __restrict__ out) {
    const int tid = threadIdx.x;
    const int chunk = blockIdx.x >> 2;
    const int b = (blockIdx.x & 3) * 64 + tid;
    const float* Ws[4] = {Wf, Wi, Wu, Wo};
    const float* Ps[4] = {pf, pi, pu, po};

    // deterministic finals for the hx / cx rows (only chunk NCH-1 uses them)
    float cd[2], hd[2];
#pragma unroll
    for (int w = 0; w < 2; ++w) {
        const int q = w + 2;
        float fv = 1.0f / (1.0f + expf(-cosf(Ps[0][q])));
        float iv = 1.0f / (1.0f + expf(-cosf(Ps[1][q])));
        float gv = tanhf(cosf(Ps[2][q]));
        float ov = 1.0f / (1.0f + expf(-cosf(Ps[3][q])));
        float l2f = log2f(fv);
        float S = iv * gv;
        float ric = 1.0f / (1.0f - fv);
        cd[w] = S * (1.0f - exp2f(512.0f * l2f)) * ric;
        hd[w] = ov * tanhf(cd[w]);
    }

    v2f wa[4], wb[4];
#pragma unroll
    for (int g = 0; g < 4; ++g) {
        wa[g].x = Ws[g][256] * INV2PI;
        wa[g].y = Ws[g][260 + 256] * INV2PI;
        wb[g].x = Ws[g][257] * INV2PI;
        wb[g].y = Ws[g][260 + 257] * INV2PI;
    }

    const int t0 = chunk * CHUNK;
    const int tw = (t0 - WARM > 0) ? (t0 - WARM) : 0;  // chunk 0 -> 0
    const int len = t0 + CHUNK - tw;                   // 32 or 56 (%8 == 0)

    v2f h = (v2f)(0.0f), c = (v2f)(0.0f);
    const float* Zb = Z + (size_t)b * 8;  // row t at +t*2048 floats
    float* outp = out + (size_t)b * 4;
    v4f zbuf[8][2];
#pragma unroll
    for (int s = 0; s < 8; ++s) {
        zbuf[s][0] = *(const v4f*)(Zb + (size_t)(tw + s) * 2048);
        zbuf[s][1] = *(const v4f*)(Zb + (size_t)(tw + s) * 2048 + 4);
    }

#pragma unroll 8
    for (int s = 0; s < len; ++s) {
        const int t = tw + s;
        const int slot = s & 7;
        v4f zA = zbuf[slot][0], zB = zbuf[slot][1];
        if (s + 8 < len) {
            zbuf[slot][0] = *(const v4f*)(Zb + (size_t)(t + 8) * 2048);
            zbuf[slot][1] = *(const v4f*)(Zb + (size_t)(t + 8) * 2048 + 4);
        }
        v2f zf = {zA.x, zA.y}, zi = {zA.z, zA.w}, zu = {zB.x, zB.y}, zo = {zB.z, zB.w};
        v2f h0s = (v2f)(h.x), h1s = (v2f)(h.y);
        v2f af = pkfma(h0s, wa[0], pkfma(h1s, wb[0], zf));
        v2f ai = pkfma(h0s, wa[1], pkfma(h1s, wb[1], zi));
        v2f au = pkfma(h0s, wa[2], pkfma(h1s, wb[2], zu));
        v2f ao = pkfma(h0s, wa[3], pkfma(h1s, wb[3], zo));
        v2f f = sig2(cos2(af));
        v2f i = sig2(cos2(ai));
        v2f g = tanh2(cos2(au));
        v2f o = sig2(cos2(ao));
        c = pkfma(f, c, i * g);
        v2f th = tanh2(c);
        h = o * th;
        if (t >= t0)
            *(v2f*)(outp + (size_t)t * (BB * 4)) = h;  // cols 0,1 (2,3 by gemm)
    }

    if (chunk == NCH - 1) {
        *(float4*)(out + (size_t)TT * BB * 4 + (size_t)b * 4) =
            make_float4(h.x, h.y, hd[0], hd[1]);
        *(float4*)(out + (size_t)TT * BB * 4 + (size_t)BB * 4 + (size_t)b * 4) =
            make_float4(c.x, c.y, cd[0], cd[1]);
    }
}

extern "C" void kernel_launch(void* const* d_in, const int* in_sizes, int n_in,
                              void* d_out, int out_size, void* d_ws, size_t ws_size,
                              hipStream_t stream) {
    (void)in_sizes; (void)n_in; (void)out_size; (void)ws_size;
    const float* x  = (const float*)d_in[0];
    const float* Wf = (const float*)d_in[1];
    const float* bf = (const float*)d_in[2];
    const float* pf = (const float*)d_in[3];
    const float* Wi = (const float*)d_in[4];
    const float* bi = (const float*)d_in[5];
    const float* pi = (const float*)d_in[6];
    const float* Wu = (const float*)d_in[7];
    const float* bu = (const float*)d_in[8];
    const float* pu = (const float*)d_in[9];
    const float* Wo = (const float*)d_in[10];
    const float* bo = (const float*)d_in[11];
    const float* po = (const float*)d_in[12];
    float* out = (float*)d_out;
    float* Z = (float*)d_ws;  // T*B*8*4 = 4 MiB

    qlstm_gemm<<<2048, 256, 0, stream>>>(x, Wf, bf, pf, Wi, bi, pi, Wu, bu, pu,
                                         Wo, bo, po, Z, out);
    qlstm_scan<<<NCH * 4, 64, 0, stream>>>(Z, Wf, pf, Wi, pi, Wu, pu, Wo, po, out);
}